// Round 3
// baseline (96.633 us; speedup 1.0000x reference)
//
#include <hip/hip_runtime.h>
#include <hip/hip_bf16.h>

// out[b,0,o0,o1,o2] = in[b, 1 + (n*14+g1)*14 + g2, ch]
//   i0 = floor(o0*144/64) -> o0 = 4n+o0loc, c0 = 2*o0loc  (o0loc 0..3)
//   i1 = floor(o1*63/32)  -> g1 = i1/9, c1 = i1%9
//   i2 = floor(o2*63/32)  -> g2 = i2/9, c2 = i2%9
//   cc = c0*81 + c1*9 + c2 ; ch = floorf(cc * fl32(768/729))   (bit-exact vs JAX)
//
// Block = (b, n, g1). Stage 14 tokens x 4 channel bands (92 floats each,
// bases {0,168,340,508} - band3 min ch is 511: fl32(486*S) rounds DOWN to
// 511.99997) into LDS with contiguous float4 bursts, then gather + coalesced
// stores. Converts ~300 MB of scattered line fetches into streaming reads.

#define TOKENS 3137
#define CHANNELS 768
#define BANDW 92           // floats per band (covers max width 89)
#define TOKSTRIDE 372      // 4*BANDW + 4 pad floats (372 mod 32 = 20: bank spread)

__global__ __launch_bounds__(256) void gather_lds_kernel(const float* __restrict__ in,
                                                         float* __restrict__ out) {
    const float ch_scale = (float)(768.0 / 729.0);   // fl32, identical to JAX
    __shared__ float lds[14 * TOKSTRIDE];            // 20832 B

    int bx = blockIdx.x;
    int g1 = bx % 14;
    int r  = bx / 14;
    int n  = r & 15;
    int b  = r >> 4;

    int tid = threadIdx.x;
    int tbase = 1 + (n * 14 + g1) * 14;
    long long rowbase = (long long)(b * TOKENS + tbase) * CHANNELS;

    // ---- load phase: 14 tokens x 4 bands x 23 float4 (+1 pad slot skipped) ----
    float4* lds4 = (float4*)lds;
    for (int idx = tid; idx < 14 * 93; idx += 256) {
        int g2 = idx / 93;
        int r2 = idx - 93 * g2;
        if (r2 < 92) {
            int band  = r2 / 23;
            int chunk = r2 - 23 * band;
            int bb = 170 * band - 2 * (band & 1);    // 0,168,340,508
            const float4* src =
                (const float4*)(in + rowbase + (long long)g2 * CHANNELS + bb);
            lds4[idx] = src[chunk];                  // float off: g2*372+band*92+chunk*4
        }
    }
    __syncthreads();

    // ---- gather phase ----
    int o2 = tid & 63;
    int i2 = (o2 * 63) >> 5;
    int g2 = i2 / 9;
    int c2 = i2 - 9 * g2;
    int lane_o1 = tid >> 6;                          // 0..3

    int o1s  = (32 * g1 + 6) / 7;                    // ceil(32*g1/7)
    int cnt1 = (32 * (g1 + 1) + 6) / 7 - o1s;        // 4 or 5

    const float* ldsg2 = lds + g2 * TOKSTRIDE;

    for (int o0loc = 0; o0loc < 4; ++o0loc) {
        int bb = 170 * o0loc - 2 * (o0loc & 1);      // band base in channels
        int ccb = 162 * o0loc;                       // c0*81, c0 = 2*o0loc
        const float* ldsrow = ldsg2 + o0loc * BANDW - bb;
        int o0 = 4 * n + o0loc;
        for (int o1loc = lane_o1; o1loc < cnt1; o1loc += 4) {
            int o1 = o1s + o1loc;
            int i1 = (o1 * 63) >> 5;
            int c1 = i1 - 9 * g1;
            int cc = ccb + c1 * 9 + c2;
            int ch = (int)floorf((float)cc * ch_scale);
            float v = ldsrow[ch];
            out[(((b * 64 + o0) * 64 + o1) << 6) | o2] = v;
        }
    }
}

extern "C" void kernel_launch(void* const* d_in, const int* in_sizes, int n_in,
                              void* d_out, int out_size, void* d_ws, size_t ws_size,
                              hipStream_t stream) {
    const float* in = (const float*)d_in[0];
    float* out = (float*)d_out;
    int blocks = 64 * 16 * 14;   // (b, n, g1) = 14336
    gather_lds_kernel<<<blocks, 256, 0, stream>>>(in, out);
}

// Round 4
// 88.559 us; speedup vs baseline: 1.0912x; 1.0912x over previous
//
#include <hip/hip_runtime.h>
#include <hip/hip_bf16.h>

// out[b,0,o0,o1,o2] = in[b, 1 + (n*14+g1)*14 + g2, ch]
//   o0 = 4n + o0loc -> c0 = floor(9*o0loc/4) = 2*o0loc, band = o0loc
//   i1 = floor(63*o1/32) -> g1 = i1/9, c1 = i1%9
//   i2 = floor(63*o2/32) -> g2 = i2/9, c2 = i2%9
//   cc = 162*o0loc + 9*c1 + c2 ; ch = floorf(cc * fl32(768/729))  (bit-exact vs JAX)
//
// Block = (b,n,g1). Stage 14 tokens x 14 aligned 128B lines via
// global_load_lds width=16 (async, linear LDS dest, per-lane global src).
// Band windows (floats): [0,96) [160,256) [320,448) [480,608)
//   cover ch ranges      [0,88] [170,254] [341,425] [511,596].
// Fetch = 14336 blocks * 14 tok * 1792 B = 360 MB aligned streaming.

#define TOKENS 3137
#define CHANNELS 768
#define ROWBYTES 3072
#define TOKCHUNKS 114           // 112 data chunks (16B) + 2 pad
#define TOKSTRIDEF 456          // floats per token in LDS (456 mod 32 = 8: bank spread)
#define NCHUNKS (14 * TOKCHUNKS) // 1596
#define LDSFLOATS (NCHUNKS * 4)  // 25536 B

__global__ __launch_bounds__(256) void gather_glds_kernel(const float* __restrict__ in,
                                                          float* __restrict__ out) {
    const float ch_scale = (float)(768.0 / 729.0);  // fl32, identical to JAX
    __shared__ float lds[LDSFLOATS];

    int bx = blockIdx.x;
    int g1 = bx % 14;
    int r0 = bx / 14;
    int n  = r0 & 15;
    int b  = r0 >> 4;

    int tid = threadIdx.x;
    int tbase = 1 + (n * 14 + g1) * 14;
    const char* rowp = (const char*)(in + (long long)(b * TOKENS + tbase) * CHANNELS);

    // ---- async load phase: 1596 chunks of 16B, linear LDS, banded global src ----
    #pragma unroll
    for (int k = 0; k < 7; ++k) {
        int ci = tid + 256 * k;
        if (ci < NCHUNKS) {
            int g2 = ci / TOKCHUNKS;
            int r  = ci - TOKCHUNKS * g2;
            // bands: r<24 -> base 0 ; <48 -> 640 ; <80 -> 1280 ; <112 -> 1920
            int byteoff = r * 16 + ((int)(r >= 24) + (int)(r >= 48)) * 256
                                 + (int)(r >= 80) * 128;
            if (r >= 112) byteoff = 0;   // pad chunk: reload line 0 (no extra line)
            const char* src = rowp + g2 * ROWBYTES + byteoff;
            __builtin_amdgcn_global_load_lds(
                (const __attribute__((address_space(1))) void*)src,
                (__attribute__((address_space(3))) void*)&lds[ci * 4],
                16, 0, 0);
        }
    }
    __syncthreads();

    // ---- gather phase ----
    int o2 = tid & 63;
    int i2 = (o2 * 63) >> 5;
    int g2 = i2 / 9;
    int c2 = i2 - 9 * g2;
    int lane_o1 = tid >> 6;                     // 0..3

    int o1s  = (32 * g1 + 6) / 7;               // ceil(32*g1/7)
    int cnt1 = (32 * (g1 + 1) + 6) / 7 - o1s;   // 4 or 5

    // lds float offset = g2*456 + K[band] + ch ; K = bandOff - chBase
    const int K[4] = {0 - 0, 96 - 160, 192 - 320, 320 - 480}; // {0,-64,-128,-160}
    const float* ldsg2 = lds + g2 * TOKSTRIDEF;

    #pragma unroll
    for (int o0loc = 0; o0loc < 4; ++o0loc) {
        int o0  = 4 * n + o0loc;
        int ccb = 162 * o0loc;
        for (int o1loc = lane_o1; o1loc < cnt1; o1loc += 4) {
            int o1 = o1s + o1loc;
            int i1 = (o1 * 63) >> 5;
            int c1 = i1 - 9 * g1;
            int cc = ccb + c1 * 9 + c2;
            int ch = (int)floorf((float)cc * ch_scale);
            out[(((b * 64 + o0) * 64 + o1) << 6) | o2] = ldsg2[K[o0loc] + ch];
        }
    }
}

extern "C" void kernel_launch(void* const* d_in, const int* in_sizes, int n_in,
                              void* d_out, int out_size, void* d_ws, size_t ws_size,
                              hipStream_t stream) {
    const float* in = (const float*)d_in[0];
    float* out = (float*)d_out;
    int blocks = 64 * 16 * 14;   // (b, n, g1) = 14336
    gather_glds_kernel<<<blocks, 256, 0, stream>>>(in, out);
}

// Round 5
// 81.740 us; speedup vs baseline: 1.1822x; 1.0834x over previous
//
#include <hip/hip_runtime.h>
#include <hip/hip_bf16.h>

// out[b,0,o0,o1,o2] = in[b, 1 + (n*14+g1)*14 + g2, ch]
//   i0 = floor(o0*144/64); n = i0/9; c0 = i0%9
//   i1 = floor(o1*126/64); g1 = i1/9; c1 = i1%9
//   i2 = floor(o2*126/64); g2 = i2/9; c2 = i2%9
//   cc = (c0*9+c1)*9+c2; ch = floorf(cc * fl32(768/729))  (bit-exact vs JAX)
//
// R2 structure (direct gather, 4 tokens/thread sharing one ch computation:
// o0 -> o0+16 gives i0 += 36 -> same c0/ch, token += 784) PLUS chunked
// XCD-aware block swizzle: consecutive logical blocks (which share token-row
// cache lines across adjacent o1 windows) land on the SAME XCD's L2 instead
// of being round-robined across 8 XCDs. 16384 blocks % 8 == 0 -> bijective.

#define TOKENS 3137
#define CHANNELS 768

__global__ __launch_bounds__(256) void gather4_swz_kernel(const float* __restrict__ in,
                                                          float* __restrict__ out) {
    const float ch_scale = (float)(768.0 / 729.0);  // f32-rounded, same as JAX

    // chunked XCD swizzle: HW assigns XCD = blockIdx % 8; give each XCD a
    // contiguous 2048-block chunk of the logical grid.
    int bid = blockIdx.x;
    int wg  = (bid & 7) * 2048 + (bid >> 3);

    int gid = wg * 256 + threadIdx.x;
    int o2 = gid & 63;
    int r  = gid >> 6;
    int o1 = r & 63;
    r >>= 6;
    int q  = r & 15;   // o0 base: o0 = q + 16*j, j=0..3
    int b  = r >> 4;

    int i0 = (q  * 144) >> 6;   // floor(9q/4), 0..33
    int i1 = (o1 * 126) >> 6;
    int i2 = (o2 * 126) >> 6;

    int nq = i0 / 9, c0 = i0 - nq * 9;
    int g1 = i1 / 9, c1 = i1 - g1 * 9;
    int g2 = i2 / 9, c2 = i2 - g2 * 9;

    int cc = (c0 * 9 + c1) * 9 + c2;
    int ch = (int)floorf((float)cc * ch_scale);

    int t = 1 + (nq * 14 + g1) * 14 + g2;

    const float* src = in + ((long long)(b * TOKENS + t) * CHANNELS + ch);
    // 4 independent loads (different tokens, same channel)
    float v0 = src[0];
    float v1 = src[1 * 784 * CHANNELS];
    float v2 = src[2 * 784 * CHANNELS];
    float v3 = src[3 * 784 * CHANNELS];

    float* dst = out + ((((b << 6) | q) << 6 | o1) << 6 | o2);
    dst[0 << 16] = v0;   // o0 = q
    dst[1 << 16] = v1;   // o0 = q+16
    dst[2 << 16] = v2;   // o0 = q+32
    dst[3 << 16] = v3;   // o0 = q+48
}

extern "C" void kernel_launch(void* const* d_in, const int* in_sizes, int n_in,
                              void* d_out, int out_size, void* d_ws, size_t ws_size,
                              hipStream_t stream) {
    const float* in = (const float*)d_in[0];
    float* out = (float*)d_out;
    // total threads = 64(b) * 16(q) * 64(o1) * 64(o2) = 4,194,304
    int blocks = 4194304 / 256;  // 16384, divisible by 8 (bijective swizzle)
    gather4_swz_kernel<<<blocks, 256, 0, stream>>>(in, out);
}

// Round 6
// 79.837 us; speedup vs baseline: 1.2104x; 1.0238x over previous
//
#include <hip/hip_runtime.h>
#include <hip/hip_bf16.h>

// out[b,0,o0,o1,o2] = in[b, 1 + (n*14+g1)*14 + g2, ch]
//   o0 = 4n + o0loc (o0loc 0..3) -> i0 = 9n + floor(9*o0loc/4): n, c0 = {0,2,4,6}
//   i1 = floor(126*o1/64) -> g1 = i1/9, c1 = i1%9
//   i2 = floor(126*o2/64) -> g2 = i2/9, c2 = i2%9
//   cc = 81*c0/... = 162*o0loc + 9*c1 + c2 ; ch = floorf(cc * fl32(768/729))
//
// R6 restructure: thread's 4 outputs share ONE token row (4 channel bands)
// instead of one channel in 4 far-apart rows. Wave footprint = 14 consecutive
// token rows (42 KB contiguous); block sweep covers the input in monotone
// address order -> DRAM page locality on the 56%-duty line-granular read.

#define TOKENS 3137
#define CHANNELS 768

__global__ __launch_bounds__(256) void gather_row4_kernel(const float* __restrict__ in,
                                                          float* __restrict__ out) {
    const float ch_scale = (float)(768.0 / 729.0);  // fl32, identical to JAX

    // chunked XCD swizzle (proven null-cost; keeps g1-straddle sharing in one L2)
    int bid = blockIdx.x;
    int wg  = (bid & 7) * 2048 + (bid >> 3);

    int gid = wg * 256 + threadIdx.x;
    int o2 = gid & 63;
    int r  = gid >> 6;
    int o1 = r & 63;
    r >>= 6;
    int n  = r & 15;
    int b  = r >> 4;

    int i1 = (o1 * 126) >> 6;
    int i2 = (o2 * 126) >> 6;

    int g1 = i1 / 9, c1 = i1 - 9 * g1;
    int g2 = i2 / 9, c2 = i2 - 9 * g2;

    int cc0 = 9 * c1 + c2;                 // [0,80]
    int t   = 1 + (n * 14 + g1) * 14 + g2;

    const float* row = in + (long long)(b * TOKENS + t) * CHANNELS;

    // 4 channel computations + 4 loads within one 3 KB row
    float v[4];
    #pragma unroll
    for (int j = 0; j < 4; ++j) {
        int cc = 162 * j + cc0;
        int ch = (int)floorf((float)cc * ch_scale);
        v[j] = row[ch];
    }

    float* dst = out + ((((long long)(b << 6) | (n << 2)) << 6 | o1) << 6 | o2);
    #pragma unroll
    for (int j = 0; j < 4; ++j)
        dst[(long long)j << 12] = v[j];    // o0 = 4n + j, stride 64*64 floats
}

extern "C" void kernel_launch(void* const* d_in, const int* in_sizes, int n_in,
                              void* d_out, int out_size, void* d_ws, size_t ws_size,
                              hipStream_t stream) {
    const float* in = (const float*)d_in[0];
    float* out = (float*)d_out;
    // threads = 64(b) * 16(n) * 64(o1) * 64(o2) = 4,194,304 ; 4 outputs each
    int blocks = 4194304 / 256;  // 16384, divisible by 8 (bijective swizzle)
    gather_row4_kernel<<<blocks, 256, 0, stream>>>(in, out);
}

// Round 7
// 67.964 us; speedup vs baseline: 1.4218x; 1.1747x over previous
//
#include <hip/hip_runtime.h>
#include <hip/hip_bf16.h>

// out[b,0,o0,o1,o2] = in[b, 1 + (n*14+g1)*14 + g2, ch]
//   o0 = 4n + o0loc (o0loc 0..3) -> n, c0 = 2*o0loc
//   i1 = floor(126*o1/64) -> g1 = i1/9, c1 = i1%9
//   i2 = floor(126*o2/64) -> g2 = i2/9, c2 = i2%9
//   cc = 162*o0loc + 9*c1 + c2 ; ch = floorf(cc * fl32(768/729))  (bit-exact vs JAX)
//
// R6 structure (thread's 4 outputs share one token row; wave sweeps 14
// consecutive rows; monotone global order; XCD chunk swizzle) + NONTEMPORAL
// stores: the 67 MB write stream otherwise write-allocates in L2 and evicts
// read lines between their 2-3 uses (c1-multiplicity across adjacent o1
// blocks), causing ~20% HBM read refetch.

#define TOKENS 3137
#define CHANNELS 768

__global__ __launch_bounds__(256) void gather_row4_nt_kernel(const float* __restrict__ in,
                                                             float* __restrict__ out) {
    const float ch_scale = (float)(768.0 / 729.0);  // fl32, identical to JAX

    int bid = blockIdx.x;
    int wg  = (bid & 7) * 2048 + (bid >> 3);        // chunked XCD swizzle (bijective)

    int gid = wg * 256 + threadIdx.x;
    int o2 = gid & 63;
    int r  = gid >> 6;
    int o1 = r & 63;
    r >>= 6;
    int n  = r & 15;
    int b  = r >> 4;

    int i1 = (o1 * 126) >> 6;
    int i2 = (o2 * 126) >> 6;

    int g1 = i1 / 9, c1 = i1 - 9 * g1;
    int g2 = i2 / 9, c2 = i2 - 9 * g2;

    int cc0 = 9 * c1 + c2;                 // [0,80]
    int t   = 1 + (n * 14 + g1) * 14 + g2;

    const float* row = in + (long long)(b * TOKENS + t) * CHANNELS;

    float v[4];
    #pragma unroll
    for (int j = 0; j < 4; ++j) {
        int cc = 162 * j + cc0;
        int ch = (int)floorf((float)cc * ch_scale);
        v[j] = row[ch];
    }

    float* dst = out + ((((long long)(b << 6) | (n << 2)) << 6 | o1) << 6 | o2);
    #pragma unroll
    for (int j = 0; j < 4; ++j)
        __builtin_nontemporal_store(v[j], &dst[(long long)j << 12]);  // o0 = 4n+j
}

extern "C" void kernel_launch(void* const* d_in, const int* in_sizes, int n_in,
                              void* d_out, int out_size, void* d_ws, size_t ws_size,
                              hipStream_t stream) {
    const float* in = (const float*)d_in[0];
    float* out = (float*)d_out;
    int blocks = 4194304 / 256;  // 16384, divisible by 8 (bijective swizzle)
    gather_row4_nt_kernel<<<blocks, 256, 0, stream>>>(in, out);
}